// Round 1
// baseline (1320.386 us; speedup 1.0000x reference)
//
#include <hip/hip_runtime.h>
#include <stdint.h>

// Problem sizes (fixed)
#define S_ 256
#define B_ 64
#define D_ 512
#define T_ 64
#define V_ 32000

typedef __attribute__((ext_vector_type(8))) short bf16x8;
typedef __attribute__((ext_vector_type(8))) unsigned short u16x8;
typedef __attribute__((ext_vector_type(4))) float f32x4;

__device__ __forceinline__ unsigned short f2bf(float f) {
  union { float f; uint32_t u; } v; v.f = f;
  uint32_t r = v.u + 0x7fffu + ((v.u >> 16) & 1u);
  return (unsigned short)(r >> 16);
}
__device__ __forceinline__ float bf2f(unsigned short u) {
  union { uint32_t u; float f; } v; v.u = ((uint32_t)u) << 16;
  return v.f;
}

__device__ __forceinline__ void async16(const void* g, void* l) {
  __builtin_amdgcn_global_load_lds((const __attribute__((address_space(1))) void*)g,
                                   (__attribute__((address_space(3))) void*)l, 16, 0, 0);
}

// flat copy nbytes (multiple of 4096) global->LDS, 256 threads, 16B/lane
__device__ __forceinline__ void stage_flat(const void* g, void* l, int nbytes, int tid) {
  const char* gc = (const char*)g;
  char* lc = (char*)l;
  for (int off = tid * 16; off < nbytes; off += 4096) async16(gc + off, lc + off);
}

// stage nrows rows x 64 bf16 cols (128B/row) from g (row stride rs elems) -> lds linear [nrows][64]
__device__ __forceinline__ void stage_rows(const unsigned short* g, int rs,
                                           unsigned short* l, int nrows, int tid) {
  const int r0 = tid >> 3;
  const int c = (tid & 7) * 8;
  for (int r = r0; r < nrows; r += 32) async16(g + (size_t)r * rs + c, l + r * 64 + c);
}

// ---------------- prep kernels ----------------
__global__ __launch_bounds__(256) void cast_bf16(const float* __restrict__ in,
                                                 unsigned short* __restrict__ out, int n8) {
  int i = blockIdx.x * blockDim.x + threadIdx.x;
  const int stride = gridDim.x * blockDim.x;
  for (; i < n8; i += stride) {
    const float4* p = (const float4*)(in + (size_t)i * 8);
    float4 a = p[0], c = p[1];
    u16x8 o;
    o[0] = f2bf(a.x); o[1] = f2bf(a.y); o[2] = f2bf(a.z); o[3] = f2bf(a.w);
    o[4] = f2bf(c.x); o[5] = f2bf(c.y); o[6] = f2bf(c.z); o[7] = f2bf(c.w);
    *(u16x8*)(out + (size_t)i * 8) = o;
  }
}

__global__ __launch_bounds__(256) void bias_sum_k(const float* __restrict__ a,
                                                  const float* __restrict__ b,
                                                  float* __restrict__ o) {
  int i = blockIdx.x * blockDim.x + threadIdx.x;
  if (i < 2048) o[i] = a[i] + b[i];
}

// h0 = c0 = feats[S-1]  (h0 bf16 into Hbuf row block 0; c0 f32)
__global__ __launch_bounds__(256) void init_hc(const float* __restrict__ feats,
                                               float* __restrict__ c_state,
                                               unsigned short* __restrict__ Hbuf,
                                               unsigned short* __restrict__ Hlo) {
  int i = blockIdx.x * blockDim.x + threadIdx.x;  // 32768
  float f = feats[(size_t)(S_ - 1) * B_ * D_ + i];
  c_state[i] = f;
  unsigned short hi = f2bf(f);
  Hbuf[i] = hi;
  Hlo[i] = f2bf(f - bf2f(hi));
}

// feats [S,B,D] f32 -> fb/fb_lo [B,S,D] bf16 (row permute, hi+lo split)
__global__ __launch_bounds__(256) void feats_perm(const float* __restrict__ feats,
                                                  unsigned short* __restrict__ fb,
                                                  unsigned short* __restrict__ fbl) {
  const int rid = blockIdx.x * 4 + (threadIdx.x >> 6);  // s*64+b
  const int lane = threadIdx.x & 63;
  const int s = rid >> 6, b = rid & 63;
  const float* src = feats + (size_t)rid * D_ + lane * 8;
  float4 a = ((const float4*)src)[0], c = ((const float4*)src)[1];
  float x[8] = {a.x, a.y, a.z, a.w, c.x, c.y, c.z, c.w};
  u16x8 hi, lo;
#pragma unroll
  for (int e = 0; e < 8; ++e) {
    unsigned short h = f2bf(x[e]);
    hi[e] = h;
    lo[e] = f2bf(x[e] - bf2f(h));
  }
  const size_t orow = ((size_t)b * S_ + s) * D_ + lane * 8;
  *(u16x8*)(fb + orow) = hi;
  *(u16x8*)(fbl + orow) = lo;
}

// feats [S,B,D] f32 -> fT [B,D,S] bf16 (inner transpose)
__global__ __launch_bounds__(256) void feats_tr(const float* __restrict__ feats,
                                                unsigned short* __restrict__ fT) {
  __shared__ float tile[32][33];
  const int b = blockIdx.z, d0 = blockIdx.x * 32, s0 = blockIdx.y * 32;
  const int i = threadIdx.x >> 5, jj = threadIdx.x & 31;
  for (int ii = i; ii < 32; ii += 8)
    tile[ii][jj] = feats[((size_t)(s0 + ii) * B_ + b) * D_ + d0 + jj];
  __syncthreads();
  for (int ii = i; ii < 32; ii += 8)
    fT[((size_t)b * D_ + d0 + ii) * S_ + s0 + jj] = f2bf(tile[jj][ii]);
}

// X[t*64+b] = vocab_bf[labels[b,t]]
__global__ __launch_bounds__(256) void embed_k(const int* __restrict__ labels,
                                               const unsigned short* __restrict__ vocab,
                                               unsigned short* __restrict__ X) {
  const int rid = blockIdx.x * 4 + (threadIdx.x >> 6);  // t*64+b
  const int lane = threadIdx.x & 63;
  const int t = rid >> 6, b = rid & 63;
  const int lbl = labels[b * T_ + t];
  *(u16x8*)(X + (size_t)rid * D_ + lane * 8) =
      *(const u16x8*)(vocab + (size_t)lbl * D_ + lane * 8);
}

// ---------------- NT GEMM: C[M,N] = A[M,K] * B[N,K]^T + bias[n] ----------------
// 128x128 tile, BK=64, 256 thr (4 waves, each 64x64 = 4x4 16x16 frags)
__global__ __launch_bounds__(256) void gemm_nt(const unsigned short* __restrict__ A,
                                               const unsigned short* __restrict__ B,
                                               const float* __restrict__ bias,
                                               float* __restrict__ C, int K, int ldc) {
  __shared__ unsigned short As[128 * 64];
  __shared__ unsigned short Bs[128 * 64];
  const int tid = threadIdx.x;
  // XCD-aware bijective swizzle (nwg % 8 == 0 for both uses)
  const int nwg = gridDim.x * gridDim.y;
  const int orig = blockIdx.y * gridDim.x + blockIdx.x;
  const int chunk = nwg >> 3;
  const int swz = (orig & 7) * chunk + (orig >> 3);
  const int m0 = (swz / gridDim.x) * 128, n0 = (swz % gridDim.x) * 128;

  const int w = tid >> 6, lane = tid & 63, lr = lane & 15, lg = lane >> 4;
  const int wr = (w & 1) * 64, wc = (w >> 1) * 64;

  f32x4 acc[4][4];
#pragma unroll
  for (int i = 0; i < 4; ++i)
#pragma unroll
    for (int j = 0; j < 4; ++j) acc[i][j] = {0.f, 0.f, 0.f, 0.f};

  const unsigned short* Ab = A + (size_t)m0 * K;
  const unsigned short* Bb = B + (size_t)n0 * K;
  const int nk = K >> 6;
  for (int kt = 0; kt < nk; ++kt) {
    stage_rows(Ab + kt * 64, K, As, 128, tid);
    stage_rows(Bb + kt * 64, K, Bs, 128, tid);
    __syncthreads();
#pragma unroll
    for (int ks = 0; ks < 2; ++ks) {
      bf16x8 af[4], bfr[4];
#pragma unroll
      for (int i = 0; i < 4; ++i)
        af[i] = *(const bf16x8*)(As + (wr + i * 16 + lr) * 64 + ks * 32 + lg * 8);
#pragma unroll
      for (int j = 0; j < 4; ++j)
        bfr[j] = *(const bf16x8*)(Bs + (wc + j * 16 + lr) * 64 + ks * 32 + lg * 8);
#pragma unroll
      for (int i = 0; i < 4; ++i)
#pragma unroll
        for (int j = 0; j < 4; ++j)
          acc[i][j] = __builtin_amdgcn_mfma_f32_16x16x32_bf16(af[i], bfr[j], acc[i][j], 0, 0, 0);
    }
    __syncthreads();
  }
#pragma unroll
  for (int j = 0; j < 4; ++j) {
    const int col = n0 + wc + j * 16 + lr;
    const float bv = bias[col];
#pragma unroll
    for (int i = 0; i < 4; ++i) {
      const int row = m0 + wr + i * 16 + lg * 4;
      float* cp = C + (size_t)row * ldc + col;
#pragma unroll
      for (int r = 0; r < 4; ++r) cp[(size_t)r * ldc] = acc[i][j][r] + bv;
    }
  }
}

// ---------------- P1: one LSTM step ----------------
// grid 128 = (bb in 0..3) x (j in 0..31). WG computes gates for 16 b's x 16 d's x 4 gates.
__global__ __launch_bounds__(256) void lstm_step(const unsigned short* __restrict__ Whh,
                                                 const float* __restrict__ gx,
                                                 unsigned short* __restrict__ Hbuf,
                                                 unsigned short* __restrict__ Hlo,
                                                 float* __restrict__ c_state, int t) {
  __shared__ unsigned short As[16 * 512];
  __shared__ unsigned short Bs[64 * 512];
  const int tid = threadIdx.x;
  const int j = blockIdx.x & 31, bb = blockIdx.x >> 5;
  const int w = tid >> 6, lane = tid & 63, lr = lane & 15, lg = lane >> 4;

  stage_flat(Hbuf + ((size_t)t * 64 + bb * 16) * 512, As, 16 * 512 * 2, tid);
#pragma unroll
  for (int g = 0; g < 4; ++g)
    stage_flat(Whh + ((size_t)g * 512 + j * 16) * 512, Bs + g * 16 * 512, 16 * 512 * 2, tid);
  __syncthreads();

  f32x4 acc = {0.f, 0.f, 0.f, 0.f};
#pragma unroll
  for (int ks = 0; ks < 16; ++ks) {
    bf16x8 av = *(const bf16x8*)(As + lr * 512 + ks * 32 + lg * 8);
    bf16x8 bv = *(const bf16x8*)(Bs + (w * 16 + lr) * 512 + ks * 32 + lg * 8);
    acc = __builtin_amdgcn_mfma_f32_16x16x32_bf16(av, bv, acc, 0, 0, 0);
  }
  __syncthreads();
  float* gbuf = (float*)As;  // [4][16][16]
#pragma unroll
  for (int r = 0; r < 4; ++r) gbuf[(w * 16 + lg * 4 + r) * 16 + lr] = acc[r];
  __syncthreads();

  const int b = tid >> 4, dl = tid & 15;
  const size_t rowg = (size_t)t * 64 + bb * 16 + b;
  const int dcol = j * 16 + dl;
  const float iv = gbuf[(0 * 16 + b) * 16 + dl] + gx[rowg * 2048 + 0 * 512 + dcol];
  const float fv = gbuf[(1 * 16 + b) * 16 + dl] + gx[rowg * 2048 + 1 * 512 + dcol];
  const float gv = gbuf[(2 * 16 + b) * 16 + dl] + gx[rowg * 2048 + 2 * 512 + dcol];
  const float ov = gbuf[(3 * 16 + b) * 16 + dl] + gx[rowg * 2048 + 3 * 512 + dcol];
  const size_t ci = (size_t)(bb * 16 + b) * 512 + dcol;
  const float si = 1.f / (1.f + __expf(-iv));
  const float sf = 1.f / (1.f + __expf(-fv));
  const float so = 1.f / (1.f + __expf(-ov));
  const float cn = sf * c_state[ci] + si * tanhf(gv);
  const float hn = so * tanhf(cn);
  c_state[ci] = cn;
  const size_t ho = ((size_t)(t + 1) * 64 + bb * 16 + b) * 512 + dcol;
  const unsigned short hi = f2bf(hn);
  Hbuf[ho] = hi;
  Hlo[ho] = f2bf(hn - bf2f(hi));
}

// ---------------- P2: scores (split-bf16, 3 passes) + softmax ----------------
// grid 64 (per b). scores[t,s] = sum_d h_t[d]*feats[s,b,d]; softmax over s; write bf16 attnW[b][t][s]
__global__ __launch_bounds__(256) void attn_score(const unsigned short* __restrict__ Hhi,
                                                  const unsigned short* __restrict__ Hlo,
                                                  const unsigned short* __restrict__ fb,
                                                  const unsigned short* __restrict__ fbl,
                                                  unsigned short* __restrict__ attnW) {
  __shared__ unsigned short As[64 * 64];
  __shared__ unsigned short Bs[256 * 64];
  const int b = blockIdx.x, tid = threadIdx.x;
  const int w = tid >> 6, lane = tid & 63, lr = lane & 15, lg = lane >> 4;
  f32x4 acc[16];
#pragma unroll
  for (int j2 = 0; j2 < 16; ++j2) acc[j2] = {0.f, 0.f, 0.f, 0.f};

  const unsigned short* Aps[3] = {Hhi, Hhi, Hlo};
  const unsigned short* Bps[3] = {fb, fbl, fb};
  for (int p = 0; p < 3; ++p) {
    const unsigned short* Ag = Aps[p] + ((size_t)64 + b) * 512;   // row t stride 64*512
    const unsigned short* Bg = Bps[p] + (size_t)b * S_ * 512;
    for (int kt = 0; kt < 8; ++kt) {
      stage_rows(Ag + kt * 64, 64 * 512, As, 64, tid);
      stage_rows(Bg + kt * 64, 512, Bs, 256, tid);
      __syncthreads();
#pragma unroll
      for (int ks = 0; ks < 2; ++ks) {
        bf16x8 av = *(const bf16x8*)(As + (w * 16 + lr) * 64 + ks * 32 + lg * 8);
#pragma unroll
        for (int j2 = 0; j2 < 16; ++j2) {
          bf16x8 bv = *(const bf16x8*)(Bs + (j2 * 16 + lr) * 64 + ks * 32 + lg * 8);
          acc[j2] = __builtin_amdgcn_mfma_f32_16x16x32_bf16(av, bv, acc[j2], 0, 0, 0);
        }
      }
      __syncthreads();
    }
  }
#pragma unroll
  for (int r = 0; r < 4; ++r) {
    const int trow = w * 16 + lg * 4 + r;
    float m = -1e30f;
#pragma unroll
    for (int j2 = 0; j2 < 16; ++j2) m = fmaxf(m, acc[j2][r]);
    m = fmaxf(m, __shfl_xor(m, 1));
    m = fmaxf(m, __shfl_xor(m, 2));
    m = fmaxf(m, __shfl_xor(m, 4));
    m = fmaxf(m, __shfl_xor(m, 8));
    float s = 0.f;
    float ev[16];
#pragma unroll
    for (int j2 = 0; j2 < 16; ++j2) {
      ev[j2] = __expf(acc[j2][r] - m);
      s += ev[j2];
    }
    s += __shfl_xor(s, 1);
    s += __shfl_xor(s, 2);
    s += __shfl_xor(s, 4);
    s += __shfl_xor(s, 8);
    const float inv = 1.f / s;
#pragma unroll
    for (int j2 = 0; j2 < 16; ++j2)
      attnW[((size_t)b * 64 + trow) * S_ + j2 * 16 + lr] = f2bf(ev[j2] * inv);
  }
}

// ---------------- P3: ctx = attnW[b] @ feats_b  (via fT) ----------------
// grid 64 (per b). C[t,d] = sum_s a[t,s]*fT[d,s]; write ctx[t*64+b][d] bf16
__global__ __launch_bounds__(256) void attn_ctx(const unsigned short* __restrict__ attnW,
                                                const unsigned short* __restrict__ fT,
                                                unsigned short* __restrict__ ctx) {
  __shared__ unsigned short As[64 * 64];
  __shared__ unsigned short Bs[512 * 64];
  const int b = blockIdx.x, tid = threadIdx.x;
  const int w = tid >> 6, lane = tid & 63, lr = lane & 15, lg = lane >> 4;
  f32x4 acc[4][8];
#pragma unroll
  for (int i = 0; i < 4; ++i)
#pragma unroll
    for (int j2 = 0; j2 < 8; ++j2) acc[i][j2] = {0.f, 0.f, 0.f, 0.f};
  const unsigned short* Ag = attnW + (size_t)b * 64 * S_;
  const unsigned short* Bg = fT + (size_t)b * 512 * S_;
  for (int kt = 0; kt < 4; ++kt) {
    stage_rows(Ag + kt * 64, S_, As, 64, tid);
    stage_rows(Bg + kt * 64, S_, Bs, 512, tid);
    __syncthreads();
#pragma unroll
    for (int ks = 0; ks < 2; ++ks) {
      bf16x8 af[4];
#pragma unroll
      for (int i = 0; i < 4; ++i)
        af[i] = *(const bf16x8*)(As + (i * 16 + lr) * 64 + ks * 32 + lg * 8);
#pragma unroll
      for (int j2 = 0; j2 < 8; ++j2) {
        bf16x8 bv = *(const bf16x8*)(Bs + (w * 128 + j2 * 16 + lr) * 64 + ks * 32 + lg * 8);
#pragma unroll
        for (int i = 0; i < 4; ++i)
          acc[i][j2] = __builtin_amdgcn_mfma_f32_16x16x32_bf16(af[i], bv, acc[i][j2], 0, 0, 0);
      }
    }
    __syncthreads();
  }
#pragma unroll
  for (int i = 0; i < 4; ++i)
#pragma unroll
    for (int j2 = 0; j2 < 8; ++j2)
#pragma unroll
      for (int r = 0; r < 4; ++r) {
        const int trow = i * 16 + lg * 4 + r, col = w * 128 + j2 * 16 + lr;
        ctx[((size_t)trow * 64 + b) * 512 + col] = f2bf(acc[i][j2][r]);
      }
}

// ---------------- P4: pe = tanh(LN([h;ctx] @ Whc^T + bhc)) ----------------
// grid 64; WG g: rows [64g,64g+64) of M=4096, full N=512, K=1024
__global__ __launch_bounds__(256) void pe_ln(const unsigned short* __restrict__ Hb2,
                                             const unsigned short* __restrict__ ctx,
                                             const unsigned short* __restrict__ Whc,
                                             const float* __restrict__ bhc,
                                             const float* __restrict__ lng,
                                             const float* __restrict__ lnb,
                                             unsigned short* __restrict__ pe) {
  __shared__ unsigned short As[64 * 64];
  __shared__ unsigned short Bs[512 * 64];
  __shared__ float sb[512], sg[512], sn[512];
  const int g = blockIdx.x, tid = threadIdx.x;
  const int r0 = g * 64;
  const int w = tid >> 6, lane = tid & 63, lr = lane & 15, lg = lane >> 4;
  for (int i = tid; i < 512; i += 256) {
    sb[i] = bhc[i];
    sg[i] = lng[i];
    sn[i] = lnb[i];
  }
  f32x4 acc[32];
#pragma unroll
  for (int j2 = 0; j2 < 32; ++j2) acc[j2] = {0.f, 0.f, 0.f, 0.f};
  for (int kt = 0; kt < 16; ++kt) {
    const unsigned short* Ag = (kt < 8) ? (Hb2 + (size_t)r0 * 512 + kt * 64)
                                        : (ctx + (size_t)r0 * 512 + (kt - 8) * 64);
    stage_rows(Ag, 512, As, 64, tid);
    stage_rows(Whc + kt * 64, 1024, Bs, 512, tid);
    __syncthreads();
#pragma unroll
    for (int ks = 0; ks < 2; ++ks) {
      bf16x8 av = *(const bf16x8*)(As + (w * 16 + lr) * 64 + ks * 32 + lg * 8);
#pragma unroll
      for (int j2 = 0; j2 < 32; ++j2) {
        bf16x8 bv = *(const bf16x8*)(Bs + (j2 * 16 + lr) * 64 + ks * 32 + lg * 8);
        acc[j2] = __builtin_amdgcn_mfma_f32_16x16x32_bf16(av, bv, acc[j2], 0, 0, 0);
      }
    }
    __syncthreads();
  }
#pragma unroll
  for (int r = 0; r < 4; ++r) {
    const int row = r0 + w * 16 + lg * 4 + r;
    float xv[32];
    float s1 = 0.f, s2 = 0.f;
#pragma unroll
    for (int j2 = 0; j2 < 32; ++j2) {
      const float x = acc[j2][r] + sb[j2 * 16 + lr];
      xv[j2] = x;
      s1 += x;
      s2 += x * x;
    }
    s1 += __shfl_xor(s1, 1); s1 += __shfl_xor(s1, 2); s1 += __shfl_xor(s1, 4); s1 += __shfl_xor(s1, 8);
    s2 += __shfl_xor(s2, 1); s2 += __shfl_xor(s2, 2); s2 += __shfl_xor(s2, 4); s2 += __shfl_xor(s2, 8);
    const float mean = s1 * (1.f / 512.f);
    const float rstd = rsqrtf(s2 * (1.f / 512.f) - mean * mean + 1e-5f);
#pragma unroll
    for (int j2 = 0; j2 < 32; ++j2) {
      const int col = j2 * 16 + lr;
      pe[(size_t)row * 512 + col] = f2bf(tanhf(sg[col] * (xv[j2] - mean) * rstd + sn[col]));
    }
  }
}

// ---------------- host launch ----------------
extern "C" void kernel_launch(void* const* d_in, const int* in_sizes, int n_in, void* d_out,
                              int out_size, void* d_ws, size_t ws_size, hipStream_t stream) {
  const float* feats = (const float*)d_in[0];
  const int* labels = (const int*)d_in[1];
  const float* W_ih = (const float*)d_in[2];
  const float* W_hh = (const float*)d_in[3];
  const float* b_ih = (const float*)d_in[4];
  const float* b_hh = (const float*)d_in[5];
  const float* W_hc = (const float*)d_in[6];
  const float* b_hc = (const float*)d_in[7];
  const float* ln_g = (const float*)d_in[8];
  const float* ln_b = (const float*)d_in[9];
  const float* vocab = (const float*)d_in[10];
  const float* vbias = (const float*)d_in[11];
  float* out = (float*)d_out;
  char* ws = (char*)d_ws;

  // workspace layout (bytes); total 134,750,208
  unsigned short* vocab_bf = (unsigned short*)(ws + 0);            // 32,768,000
  unsigned short* Wih_bf  = (unsigned short*)(ws + 32768000);      //  2,097,152
  unsigned short* Whh_bf  = (unsigned short*)(ws + 34865152);      //  2,097,152
  unsigned short* Whc_bf  = (unsigned short*)(ws + 36962304);      //  1,048,576
  float*          bias_s  = (float*)(ws + 38010880);               //      8,192
  unsigned short* X       = (unsigned short*)(ws + 38019072);      //  4,194,304
  unsigned short* fb      = (unsigned short*)(ws + 42213376);      // 16,777,216
  unsigned short* fbl     = (unsigned short*)(ws + 58990592);      // 16,777,216
  unsigned short* fT      = (unsigned short*)(ws + 75767808);      // 16,777,216
  unsigned short* Hbuf    = (unsigned short*)(ws + 92545024);      //  4,259,840 (65 x 64 x 512)
  unsigned short* Hlo     = (unsigned short*)(ws + 96804864);      //  4,259,840
  float*          c_state = (float*)(ws + 101064704);              //    131,072
  float*          gx      = (float*)(ws + 101195776);              // 33,554,432
  // aliased into gx region (gx dead after the recurrence):
  unsigned short* attnW   = (unsigned short*)(ws + 101195776);             // 2,097,152
  unsigned short* ctxb    = (unsigned short*)(ws + 101195776 + 2097152);   // 4,194,304
  unsigned short* pe      = (unsigned short*)(ws + 101195776 + 6291456);   // 4,194,304

  hipLaunchKernelGGL(cast_bf16, dim3(2048), dim3(256), 0, stream, vocab, vocab_bf, 2048000);
  hipLaunchKernelGGL(cast_bf16, dim3(512), dim3(256), 0, stream, W_ih, Wih_bf, 131072);
  hipLaunchKernelGGL(cast_bf16, dim3(512), dim3(256), 0, stream, W_hh, Whh_bf, 131072);
  hipLaunchKernelGGL(cast_bf16, dim3(256), dim3(256), 0, stream, W_hc, Whc_bf, 65536);
  hipLaunchKernelGGL(bias_sum_k, dim3(8), dim3(256), 0, stream, b_ih, b_hh, bias_s);
  hipLaunchKernelGGL(init_hc, dim3(128), dim3(256), 0, stream, feats, c_state, Hbuf, Hlo);
  hipLaunchKernelGGL(feats_perm, dim3(4096), dim3(256), 0, stream, feats, fb, fbl);
  hipLaunchKernelGGL(feats_tr, dim3(16, 8, 64), dim3(256), 0, stream, feats, fT);
  hipLaunchKernelGGL(embed_k, dim3(1024), dim3(256), 0, stream, labels, vocab_bf, X);

  // P0: gates_x = X @ W_ih^T + (b_ih + b_hh)   [4096 x 2048], K=512
  hipLaunchKernelGGL(gemm_nt, dim3(16, 32), dim3(256), 0, stream, X, Wih_bf, bias_s, gx, 512, 2048);

  // P1: recurrence
  for (int t = 0; t < T_; ++t)
    hipLaunchKernelGGL(lstm_step, dim3(128), dim3(256), 0, stream, Whh_bf, gx, Hbuf, Hlo,
                       c_state, t);

  // P2..P4
  hipLaunchKernelGGL(attn_score, dim3(64), dim3(256), 0, stream, Hbuf, Hlo, fb, fbl, attnW);
  hipLaunchKernelGGL(attn_ctx, dim3(64), dim3(256), 0, stream, attnW, fT, ctxb);
  hipLaunchKernelGGL(pe_ln, dim3(64), dim3(256), 0, stream, Hbuf + (size_t)64 * 512, ctxb,
                     Whc_bf, b_hc, ln_g, ln_b, pe);

  // P5: logits = pe @ vocab^T + vbias  [4096 x 32000], K=512
  hipLaunchKernelGGL(gemm_nt, dim3(250, 32), dim3(256), 0, stream, pe, vocab_bf, vbias, out, 512,
                     32000);
}